// Round 7
// baseline (491.719 us; speedup 1.0000x reference)
//
#include <hip/hip_runtime.h>
#include <hip/hip_fp16.h>
#include <math.h>

// SPAIRPointFeatureNetwork on MI355X.
//   h_{p,j} = Q[j] - G[p];  celu monotonic => segmax(celu(h)) = celu(max_j Q[j] - G[p]).
//
// R12 measured: L3_sorted = 22.2us/rep (VALUBusy 32%, HBM 21%, occ 84%) —
//   line-access bound. R9 gave per-dispatch overhead ~1.6us => R11's 177 =
//   ~18 gaps + ~22-30 L3 + ~127us of {L1,L2,memset,cell,scan,scatter,trans}:
//   models don't close by 3-5x. Suspects: trans's 4.19M random 2B perm
//   gather; same-address atomics in cell/scatter; serial 1-wave scan.
// R14 (MEASUREMENT ROUND 2): REP=8 on the four idempotent unknowns
//   (k_trans, k_scan, layer1, layer2); L3 back to REP=1. Zero functional
//   changes. Completes the cost decomposition.
//   Pre-committed: trans>20 -> fuse perm-gather into L1; sum(layers)>60 ->
//   per-cell LDS-window gather; residual(cell+scatter+gaps)>40 ->
//   atomic-free rank restructure; scan visible -> parallel scan.

#define NPTS 65536
#define KNBR 64
#define TILE 32
#define NCELL 4096

__device__ __forceinline__ float celu1(float x) {
    return x > 0.0f ? x : (__expf(x) - 1.0f);
}

__device__ __forceinline__ unsigned pkmax(unsigned a, unsigned b) {
    unsigned d;
    asm("v_pk_max_f16 %0, %1, %2" : "=v"(d) : "v"(a), "v"(b));
    return d;
}

__device__ __forceinline__ unsigned pack2(float a, float b) {
    __half2 h = __floats2half2_rn(a, b);
    return *(unsigned*)&h;
}

// ---- sort infra -----------------------------------------------------------

__global__ __launch_bounds__(256) void k_cell(
    const float* __restrict__ pos, float* __restrict__ dout, int out_size,
    int* __restrict__ cid, int* __restrict__ hist)
{
    int t = blockIdx.x * 256 + threadIdx.x;
    if (t < NPTS) {
        float p0 = pos[3 * t + 0];
        float p1 = pos[3 * t + 1];
        float p2 = pos[3 * t + 2];
        dout[3 * t + 0] = p0;
        dout[3 * t + 1] = p1;
        dout[3 * t + 2] = p2;
        int cx = min((int)(p0 * 16.0f), 15);
        int cy = min((int)(p1 * 16.0f), 15);
        int cz = min((int)(p2 * 16.0f), 15);
        int c = (cx * 16 + cy) * 16 + cz;
        cid[t] = c;
        atomicAdd(&hist[c], 1);
        for (int j = 35 * NPTS + t; j < out_size; j += NPTS)
            dout[j] = 0.0f;
    }
}

// exclusive scan of hist[4096] -> cellptr. One wave. REP for measurement.
template <int REP>
__global__ __launch_bounds__(64) void k_scan(
    const int* __restrict__ hist, int* __restrict__ cellptr)
{
#pragma unroll 1
    for (int rep = 0; rep < REP; ++rep) {
        asm volatile("" ::: "memory");
        int l = threadIdx.x;
        int v[64];
        int s = 0;
#pragma unroll
        for (int i = 0; i < 64; ++i) { v[i] = s; s += hist[l * 64 + i]; }
        int run = s;
#pragma unroll
        for (int st = 1; st < 64; st <<= 1) {
            int o = __shfl_up(run, st, 64);
            if (l >= st) run += o;
        }
        int off = run - s;
#pragma unroll
        for (int i = 0; i < 64; ++i)
            cellptr[l * 64 + i] = off + v[i];
    }
}

__global__ __launch_bounds__(256) void k_scatter(
    const float* __restrict__ pos, const int* __restrict__ cid,
    int* __restrict__ cellptr, unsigned short* __restrict__ perm,
    int* __restrict__ order, float* __restrict__ pos_s,
    const float* __restrict__ w1a, const float* __restrict__ b1a,
    __half* __restrict__ q1s)
{
    int t = blockIdx.x * 256 + threadIdx.x;
    if (t >= NPTS) return;
    int c = cid[t];
    int nid = atomicAdd(&cellptr[c], 1);
    perm[t] = (unsigned short)nid;
    order[nid] = t;
    float p0 = pos[3 * t + 0];
    float p1 = pos[3 * t + 1];
    float p2 = pos[3 * t + 2];
    pos_s[3 * nid + 0] = p0;
    pos_s[3 * nid + 1] = p1;
    pos_s[3 * nid + 2] = p2;
    float q[8];
#pragma unroll
    for (int ch = 0; ch < 8; ++ch) {
        float a = b1a[ch];
        a = fmaf(p0, w1a[0 * 8 + ch] + w1a[3 * 8 + ch], a);
        a = fmaf(p1, w1a[1 * 8 + ch] + w1a[4 * 8 + ch], a);
        a = fmaf(p2, w1a[2 * 8 + ch] + w1a[5 * 8 + ch], a);
        q[ch] = a;
    }
    uint4 pk;
    pk.x = pack2(q[0], q[1]);
    pk.y = pack2(q[2], q[3]);
    pk.z = pack2(q[4], q[5]);
    pk.w = pack2(q[6], q[7]);
    *(uint4*)(q1s + 8 * nid) = pk;
}

// translate neighbor ids to sorted space. REP for measurement (idempotent).
template <int REP>
__global__ __launch_bounds__(256) void k_trans(
    const int* __restrict__ idx, const int* __restrict__ order,
    const unsigned short* __restrict__ perm, int* __restrict__ idxs)
{
#pragma unroll 1
    for (int rep = 0; rep < REP; ++rep) {
        asm volatile("" ::: "memory");
        int g = blockIdx.x * 256 + threadIdx.x;
        int row = g >> 4;
        int j = g & 15;
        int old = order[row];
        int4 v = *(const int4*)(idx + old * KNBR + j * 4);
        int4 o;
        o.x = perm[v.x];
        o.y = perm[v.y];
        o.z = perm[v.z];
        o.w = perm[v.w];
        *(int4*)(idxs + row * KNBR + j * 4) = o;
    }
}

// ---- fused layer (sorted space) ------------------------------------------
// REP: body repeated REP times (idempotent) purely for rocprof visibility.
template <int FH, int FOUT, int FHN, bool WRITEX, int REP>
__global__ __launch_bounds__(256, 8) void k_layer(
    const __half* __restrict__ q,
    const int* __restrict__ idx,
    const float* __restrict__ pos,
    const int* __restrict__ order,
    const float* __restrict__ wap,
    const float* __restrict__ wb,
    const float* __restrict__ bb,
    const float* __restrict__ wan,
    const float* __restrict__ ban,
    float* __restrict__ xout,
    __half* __restrict__ qnext)
{
    constexpr int SL  = FH / 8;
    constexpr int LPP = SL * 8;
    constexpr int PPW = 64 / LPP;
    constexpr int NIT = TILE / (4 * PPW);

    __shared__ uint4 m_lds[TILE * SL];

    int w  = threadIdx.x >> 6;
    int l  = threadIdx.x & 63;
    int pl = l / LPP;
    int u  = l % LPP;
    int c  = u % SL;
    int g  = u / SL;
    int tb = (blockIdx.x & 255) * (NPTS / TILE / 256) + (blockIdx.x >> 8);
    int pbase = tb * TILE;

#pragma unroll 1
    for (int rep = 0; rep < REP; ++rep) {
        asm volatile("" ::: "memory");   // defeat cross-rep CSE of gathers

#pragma unroll
        for (int it = 0; it < NIT; ++it) {
            int lp = it * (4 * PPW) + w * PPW + pl;
            int p  = pbase + lp;
            const uint4* ip = (const uint4*)(idx + p * KNBR + g * 8);
            uint4 i0 = ip[0];
            uint4 i1 = ip[1];
            uint4 v[8];
            v[0] = *(const uint4*)(q + (int)i0.x * FH + c * 8);
            v[1] = *(const uint4*)(q + (int)i0.y * FH + c * 8);
            v[2] = *(const uint4*)(q + (int)i0.z * FH + c * 8);
            v[3] = *(const uint4*)(q + (int)i0.w * FH + c * 8);
            v[4] = *(const uint4*)(q + (int)i1.x * FH + c * 8);
            v[5] = *(const uint4*)(q + (int)i1.y * FH + c * 8);
            v[6] = *(const uint4*)(q + (int)i1.z * FH + c * 8);
            v[7] = *(const uint4*)(q + (int)i1.w * FH + c * 8);

            unsigned ax = 0xFC00FC00u, ay = 0xFC00FC00u, az = 0xFC00FC00u, aw = 0xFC00FC00u;
#pragma unroll
            for (int k = 0; k < 8; ++k) {
                ax = pkmax(ax, v[k].x);
                ay = pkmax(ay, v[k].y);
                az = pkmax(az, v[k].z);
                aw = pkmax(aw, v[k].w);
            }
#pragma unroll
            for (int st = SL; st < LPP; st <<= 1) {
                ax = pkmax(ax, (unsigned)__shfl_xor((int)ax, st, 64));
                ay = pkmax(ay, (unsigned)__shfl_xor((int)ay, st, 64));
                az = pkmax(az, (unsigned)__shfl_xor((int)az, st, 64));
                aw = pkmax(aw, (unsigned)__shfl_xor((int)aw, st, 64));
            }
            if (g == 0) {
                uint4 r; r.x = ax; r.y = ay; r.z = az; r.w = aw;
                m_lds[lp * SL + c] = r;
            }
        }
        __syncthreads();

        if constexpr (WRITEX) {
            if (threadIdx.x < TILE * 4) {
                int pt  = threadIdx.x >> 2;
                int qtr = threadIdx.x & 3;
                int p   = pbase + pt;
                float p0 = pos[3 * p + 0];
                float p1 = pos[3 * p + 1];
                float p2 = pos[3 * p + 2];

                float h[FH];
#pragma unroll
                for (int s = 0; s < SL; ++s) {
                    uint4 vv = m_lds[pt * SL + s];
                    unsigned w4[4] = {vv.x, vv.y, vv.z, vv.w};
#pragma unroll
                    for (int k = 0; k < 4; ++k) {
                        float2 f = __half22float2(*(__half2*)&w4[k]);
                        h[s * 8 + k * 2 + 0] = f.x;
                        h[s * 8 + k * 2 + 1] = f.y;
                    }
                }
#pragma unroll
                for (int ch = 0; ch < FH; ++ch) {
                    float gg = p0 * wap[ch] + p1 * wap[FH + ch] + p2 * wap[2 * FH + ch];
                    h[ch] = celu1(h[ch] - gg);
                }
                float x[8];
#pragma unroll
                for (int j = 0; j < 8; ++j) {
                    int c2 = qtr * 8 + j;
                    float a = bb[c2];
#pragma unroll
                    for (int ch = 0; ch < FH; ++ch)
                        a = fmaf(h[ch], wb[ch * FOUT + c2], a);
                    x[j] = celu1(a);
                }
                int oldp = order[p];
                float4* xo = (float4*)(xout + (long long)oldp * FOUT + qtr * 8);
                xo[0] = make_float4(x[0], x[1], x[2], x[3]);
                xo[1] = make_float4(x[4], x[5], x[6], x[7]);
            }
        } else if (threadIdx.x < TILE) {
            int lt = threadIdx.x;
            int p  = pbase + lt;
            float p0 = pos[3 * p + 0];
            float p1 = pos[3 * p + 1];
            float p2 = pos[3 * p + 2];

            float h[FH];
#pragma unroll
            for (int s = 0; s < SL; ++s) {
                uint4 vv = m_lds[lt * SL + s];
                unsigned w4[4] = {vv.x, vv.y, vv.z, vv.w};
#pragma unroll
                for (int k = 0; k < 4; ++k) {
                    float2 f = __half22float2(*(__half2*)&w4[k]);
                    h[s * 8 + k * 2 + 0] = f.x;
                    h[s * 8 + k * 2 + 1] = f.y;
                }
            }
#pragma unroll
            for (int ch = 0; ch < FH; ++ch) {
                float gg = p0 * wap[ch] + p1 * wap[FH + ch] + p2 * wap[2 * FH + ch];
                h[ch] = celu1(h[ch] - gg);
            }
            float x[FOUT];
#pragma unroll
            for (int c2 = 0; c2 < FOUT; ++c2) {
                float a = bb[c2];
#pragma unroll
                for (int ch = 0; ch < FH; ++ch)
                    a = fmaf(h[ch], wb[ch * FOUT + c2], a);
                x[c2] = celu1(a);
            }
            if constexpr (FHN > 0) {
                uint4* qo = (uint4*)(qnext + p * FHN);
#pragma unroll
                for (int s = 0; s < FHN / 8; ++s) {
                    float qn[8];
#pragma unroll
                    for (int k = 0; k < 8; ++k) {
                        int cn = s * 8 + k;
                        float a = ban[cn];
#pragma unroll
                        for (int c2 = 0; c2 < FOUT; ++c2)
                            a = fmaf(x[c2], wan[c2 * FHN + cn], a);
                        a = fmaf(p0, wan[(FOUT + 0) * FHN + cn], a);
                        a = fmaf(p1, wan[(FOUT + 1) * FHN + cn], a);
                        a = fmaf(p2, wan[(FOUT + 2) * FHN + cn], a);
                        qn[k] = a;
                    }
                    uint4 pk;
                    pk.x = pack2(qn[0], qn[1]);
                    pk.y = pack2(qn[2], qn[3]);
                    pk.z = pack2(qn[4], qn[5]);
                    pk.w = pack2(qn[6], qn[7]);
                    qo[s] = pk;
                }
            }
        }
        __syncthreads();
    }
}

extern "C" void kernel_launch(void* const* d_in, const int* in_sizes, int n_in,
                              void* d_out, int out_size, void* d_ws, size_t ws_size,
                              hipStream_t stream) {
    const float* pos = (const float*)d_in[0];
    const int* idx = (const int*)d_in[4];
    const float* w1a = (const float*)d_in[5];
    const float* b1a = (const float*)d_in[6];
    const float* w1b = (const float*)d_in[7];
    const float* b1b = (const float*)d_in[8];
    const float* w2a = (const float*)d_in[9];
    const float* b2a = (const float*)d_in[10];
    const float* w2b = (const float*)d_in[11];
    const float* b2b = (const float*)d_in[12];
    const float* w3a = (const float*)d_in[13];
    const float* b3a = (const float*)d_in[14];
    const float* w3b = (const float*)d_in[15];
    const float* b3b = (const float*)d_in[16];
    float* out = (float*)d_out;

    char* ws = (char*)d_ws;
    __half* A      = (__half*)ws;
    __half* B      = (__half*)(ws + (4u << 20));
    int*    idxs   = (int*)(ws + (8u << 20));
    int*    cid    = (int*)(ws + (24u << 20));
    int*    order  = (int*)(ws + (25u << 20));
    unsigned short* perm = (unsigned short*)(ws + (26u << 20));
    int*    hist   = (int*)(ws + (27u << 20));
    int*    cellptr= (int*)(ws + (27u << 20) + (64u << 10));
    float*  pos_s  = (float*)(ws + (28u << 20));

    hipMemsetAsync(hist, 0, NCELL * sizeof(int), stream);
    k_cell<<<NPTS / 256, 256, 0, stream>>>(pos, out, out_size, cid, hist);
    // MEASUREMENT: REP=8 on scan (idempotent).
    k_scan<8><<<1, 64, 0, stream>>>(hist, cellptr);
    k_scatter<<<NPTS / 256, 256, 0, stream>>>(pos, cid, cellptr, perm, order,
                                              pos_s, w1a, b1a, A);
    // MEASUREMENT: REP=8 on trans (idempotent).
    k_trans<8><<<NPTS * 16 / 256, 256, 0, stream>>>(idx, order, perm, idxs);

    // MEASUREMENT: REP=8 on layers 1 and 2 (idempotent); layer 3 known (22us).
    k_layer<8, 8, 16, false, 8><<<NPTS / TILE, 256, 0, stream>>>(
        A, idxs, pos_s, nullptr, w1a + 3 * 8, w1b, b1b, w2a, b2a, nullptr, B);
    k_layer<16, 16, 32, false, 8><<<NPTS / TILE, 256, 0, stream>>>(
        B, idxs, pos_s, nullptr, w2a + 8 * 16, w2b, b2b, w3a, b3a, nullptr, A);
    k_layer<32, 32, 0, true, 1><<<NPTS / TILE, 256, 0, stream>>>(
        A, idxs, pos_s, order, w3a + 16 * 32, w3b, b3b, nullptr, nullptr,
        out + 3 * NPTS, nullptr);
}

// Round 8
// 176.458 us; speedup vs baseline: 2.7866x; 2.7866x over previous
//
#include <hip/hip_runtime.h>
#include <hip/hip_fp16.h>
#include <math.h>

// SPAIRPointFeatureNetwork on MI355X.
//   h_{p,j} = Q[j] - G[p];  celu monotonic => segmax(celu(h)) = celu(max_j Q[j] - G[p]).
//
// Decomposition (R12+R14 bench deltas, reliable):
//   L3=22.2us, scan+trans+L1+L2=44.9 (one layer ~41 marginal under poison
//   pressure), cell+scatter+early-window ~95us. R14 profile: k_layer@REP8
//   shows WRITE_SIZE=70MB (kernel writes <8MB) => dirty-POISON EVICTION from
//   the harness's 268MB workspace fill dominates the early window; its drain
//   saturates HBM into our first ~50-80us. The invariant 177 = drain floor +
//   67us layers + infra.
// R15 (this): cut our footprint/streams. idxs -> ushort (N=65536 fits
//   EXACTLY): 8MB not 16MB. Halves trans write, 3x layer idx reads, per-lane
//   idx loads, and 8MB of eviction exposure. Workspace packed into 16MB.
//   Predict 177 -> ~158-167. If neutral => early-window floor confirmed;
//   next: infra-in-context ablation or per-cell LDS-window gather.

#define NPTS 65536
#define KNBR 64
#define TILE 32
#define NCELL 4096

__device__ __forceinline__ float celu1(float x) {
    return x > 0.0f ? x : (__expf(x) - 1.0f);
}

__device__ __forceinline__ unsigned pkmax(unsigned a, unsigned b) {
    unsigned d;
    asm("v_pk_max_f16 %0, %1, %2" : "=v"(d) : "v"(a), "v"(b));
    return d;
}

__device__ __forceinline__ unsigned pack2(float a, float b) {
    __half2 h = __floats2half2_rn(a, b);
    return *(unsigned*)&h;
}

// ---- sort infra -----------------------------------------------------------

__global__ __launch_bounds__(256) void k_cell(
    const float* __restrict__ pos, float* __restrict__ dout, int out_size,
    int* __restrict__ cid, int* __restrict__ hist)
{
    int t = blockIdx.x * 256 + threadIdx.x;
    if (t < NPTS) {
        float p0 = pos[3 * t + 0];
        float p1 = pos[3 * t + 1];
        float p2 = pos[3 * t + 2];
        dout[3 * t + 0] = p0;
        dout[3 * t + 1] = p1;
        dout[3 * t + 2] = p2;
        int cx = min((int)(p0 * 16.0f), 15);
        int cy = min((int)(p1 * 16.0f), 15);
        int cz = min((int)(p2 * 16.0f), 15);
        int c = (cx * 16 + cy) * 16 + cz;
        cid[t] = c;
        atomicAdd(&hist[c], 1);
        for (int j = 35 * NPTS + t; j < out_size; j += NPTS)
            dout[j] = 0.0f;
    }
}

// exclusive scan of hist[4096] -> cellptr. One wave.
__global__ __launch_bounds__(64) void k_scan(
    const int* __restrict__ hist, int* __restrict__ cellptr)
{
    int l = threadIdx.x;
    int v[64];
    int s = 0;
#pragma unroll
    for (int i = 0; i < 64; ++i) { v[i] = s; s += hist[l * 64 + i]; }
    int run = s;
#pragma unroll
    for (int st = 1; st < 64; st <<= 1) {
        int o = __shfl_up(run, st, 64);
        if (l >= st) run += o;
    }
    int off = run - s;
#pragma unroll
    for (int i = 0; i < 64; ++i)
        cellptr[l * 64 + i] = off + v[i];
}

__global__ __launch_bounds__(256) void k_scatter(
    const float* __restrict__ pos, const int* __restrict__ cid,
    int* __restrict__ cellptr, unsigned short* __restrict__ perm,
    int* __restrict__ order, float* __restrict__ pos_s,
    const float* __restrict__ w1a, const float* __restrict__ b1a,
    __half* __restrict__ q1s)
{
    int t = blockIdx.x * 256 + threadIdx.x;
    if (t >= NPTS) return;
    int c = cid[t];
    int nid = atomicAdd(&cellptr[c], 1);
    perm[t] = (unsigned short)nid;
    order[nid] = t;
    float p0 = pos[3 * t + 0];
    float p1 = pos[3 * t + 1];
    float p2 = pos[3 * t + 2];
    pos_s[3 * nid + 0] = p0;
    pos_s[3 * nid + 1] = p1;
    pos_s[3 * nid + 2] = p2;
    float q[8];
#pragma unroll
    for (int ch = 0; ch < 8; ++ch) {
        float a = b1a[ch];
        a = fmaf(p0, w1a[0 * 8 + ch] + w1a[3 * 8 + ch], a);
        a = fmaf(p1, w1a[1 * 8 + ch] + w1a[4 * 8 + ch], a);
        a = fmaf(p2, w1a[2 * 8 + ch] + w1a[5 * 8 + ch], a);
        q[ch] = a;
    }
    uint4 pk;
    pk.x = pack2(q[0], q[1]);
    pk.y = pack2(q[2], q[3]);
    pk.z = pack2(q[4], q[5]);
    pk.w = pack2(q[6], q[7]);
    *(uint4*)(q1s + 8 * nid) = pk;
}

// translate neighbor ids to sorted space, packed ushort (8MB not 16MB).
// 8 edges per thread: read 2x int4, write 1x ushort8 (16B).
__global__ __launch_bounds__(256) void k_trans(
    const int* __restrict__ idx, const int* __restrict__ order,
    const unsigned short* __restrict__ perm, unsigned short* __restrict__ idxs)
{
    int g = blockIdx.x * 256 + threadIdx.x;   // NPTS*8 threads
    int row = g >> 3;
    int j = g & 7;
    int old = order[row];
    const int4* src = (const int4*)(idx + old * KNBR + j * 8);
    int4 v0 = src[0];
    int4 v1 = src[1];
    uint4 o;
    o.x = (unsigned)perm[v0.x] | ((unsigned)perm[v0.y] << 16);
    o.y = (unsigned)perm[v0.z] | ((unsigned)perm[v0.w] << 16);
    o.z = (unsigned)perm[v1.x] | ((unsigned)perm[v1.y] << 16);
    o.w = (unsigned)perm[v1.z] | ((unsigned)perm[v1.w] << 16);
    *(uint4*)(idxs + row * KNBR + j * 8) = o;
}

// ---- fused layer (sorted space, ushort ids) -------------------------------
// Block = 256 threads = 4 waves, TILE=32 sorted points. Grid 2048 = 8 blk/CU.
// Tile swizzle: stride-256 dispatch->CU round-robin => one CU's 8 blocks
// share a sliding 256-point window.
template <int FH, int FOUT, int FHN, bool WRITEX>
__global__ __launch_bounds__(256, 8) void k_layer(
    const __half* __restrict__ q,            // N x FH (fp16, sorted)
    const unsigned short* __restrict__ idx,  // N x 64 (ushort sorted ids)
    const float* __restrict__ pos,           // sorted pos
    const int* __restrict__ order,           // new->old (only if WRITEX)
    const float* __restrict__ wap,
    const float* __restrict__ wb,
    const float* __restrict__ bb,
    const float* __restrict__ wan,
    const float* __restrict__ ban,
    float* __restrict__ xout,
    __half* __restrict__ qnext)
{
    constexpr int SL  = FH / 8;
    constexpr int LPP = SL * 8;
    constexpr int PPW = 64 / LPP;
    constexpr int NIT = TILE / (4 * PPW);

    __shared__ uint4 m_lds[TILE * SL];

    int w  = threadIdx.x >> 6;
    int l  = threadIdx.x & 63;
    int pl = l / LPP;
    int u  = l % LPP;
    int c  = u % SL;
    int g  = u / SL;
    int tb = (blockIdx.x & 255) * (NPTS / TILE / 256) + (blockIdx.x >> 8);
    int pbase = tb * TILE;

#pragma unroll
    for (int it = 0; it < NIT; ++it) {
        int lp = it * (4 * PPW) + w * PPW + pl;
        int p  = pbase + lp;
        // this lane's 8 edge ids in ONE 16B load (ushort-packed)
        uint4 iv = *(const uint4*)(idx + p * KNBR + g * 8);
        int e0 = iv.x & 0xffff, e1 = iv.x >> 16;
        int e2 = iv.y & 0xffff, e3 = iv.y >> 16;
        int e4 = iv.z & 0xffff, e5 = iv.z >> 16;
        int e6 = iv.w & 0xffff, e7 = iv.w >> 16;
        uint4 v[8];
        v[0] = *(const uint4*)(q + e0 * FH + c * 8);
        v[1] = *(const uint4*)(q + e1 * FH + c * 8);
        v[2] = *(const uint4*)(q + e2 * FH + c * 8);
        v[3] = *(const uint4*)(q + e3 * FH + c * 8);
        v[4] = *(const uint4*)(q + e4 * FH + c * 8);
        v[5] = *(const uint4*)(q + e5 * FH + c * 8);
        v[6] = *(const uint4*)(q + e6 * FH + c * 8);
        v[7] = *(const uint4*)(q + e7 * FH + c * 8);

        unsigned ax = 0xFC00FC00u, ay = 0xFC00FC00u, az = 0xFC00FC00u, aw = 0xFC00FC00u;
#pragma unroll
        for (int k = 0; k < 8; ++k) {
            ax = pkmax(ax, v[k].x);
            ay = pkmax(ay, v[k].y);
            az = pkmax(az, v[k].z);
            aw = pkmax(aw, v[k].w);
        }
#pragma unroll
        for (int st = SL; st < LPP; st <<= 1) {
            ax = pkmax(ax, (unsigned)__shfl_xor((int)ax, st, 64));
            ay = pkmax(ay, (unsigned)__shfl_xor((int)ay, st, 64));
            az = pkmax(az, (unsigned)__shfl_xor((int)az, st, 64));
            aw = pkmax(aw, (unsigned)__shfl_xor((int)aw, st, 64));
        }
        if (g == 0) {
            uint4 r; r.x = ax; r.y = ay; r.z = az; r.w = aw;
            m_lds[lp * SL + c] = r;
        }
    }
    __syncthreads();

    if constexpr (WRITEX) {
        if (threadIdx.x < TILE * 4) {
            int pt  = threadIdx.x >> 2;
            int qtr = threadIdx.x & 3;
            int p   = pbase + pt;
            float p0 = pos[3 * p + 0];
            float p1 = pos[3 * p + 1];
            float p2 = pos[3 * p + 2];

            float h[FH];
#pragma unroll
            for (int s = 0; s < SL; ++s) {
                uint4 vv = m_lds[pt * SL + s];
                unsigned w4[4] = {vv.x, vv.y, vv.z, vv.w};
#pragma unroll
                for (int k = 0; k < 4; ++k) {
                    float2 f = __half22float2(*(__half2*)&w4[k]);
                    h[s * 8 + k * 2 + 0] = f.x;
                    h[s * 8 + k * 2 + 1] = f.y;
                }
            }
#pragma unroll
            for (int ch = 0; ch < FH; ++ch) {
                float gg = p0 * wap[ch] + p1 * wap[FH + ch] + p2 * wap[2 * FH + ch];
                h[ch] = celu1(h[ch] - gg);
            }
            float x[8];
#pragma unroll
            for (int j = 0; j < 8; ++j) {
                int c2 = qtr * 8 + j;
                float a = bb[c2];
#pragma unroll
                for (int ch = 0; ch < FH; ++ch)
                    a = fmaf(h[ch], wb[ch * FOUT + c2], a);
                x[j] = celu1(a);
            }
            int oldp = order[p];
            float4* xo = (float4*)(xout + (long long)oldp * FOUT + qtr * 8);
            xo[0] = make_float4(x[0], x[1], x[2], x[3]);
            xo[1] = make_float4(x[4], x[5], x[6], x[7]);
        }
    } else if (threadIdx.x < TILE) {
        int lt = threadIdx.x;
        int p  = pbase + lt;
        float p0 = pos[3 * p + 0];
        float p1 = pos[3 * p + 1];
        float p2 = pos[3 * p + 2];

        float h[FH];
#pragma unroll
        for (int s = 0; s < SL; ++s) {
            uint4 vv = m_lds[lt * SL + s];
            unsigned w4[4] = {vv.x, vv.y, vv.z, vv.w};
#pragma unroll
            for (int k = 0; k < 4; ++k) {
                float2 f = __half22float2(*(__half2*)&w4[k]);
                h[s * 8 + k * 2 + 0] = f.x;
                h[s * 8 + k * 2 + 1] = f.y;
            }
        }
#pragma unroll
        for (int ch = 0; ch < FH; ++ch) {
            float gg = p0 * wap[ch] + p1 * wap[FH + ch] + p2 * wap[2 * FH + ch];
            h[ch] = celu1(h[ch] - gg);
        }
        float x[FOUT];
#pragma unroll
        for (int c2 = 0; c2 < FOUT; ++c2) {
            float a = bb[c2];
#pragma unroll
            for (int ch = 0; ch < FH; ++ch)
                a = fmaf(h[ch], wb[ch * FOUT + c2], a);
            x[c2] = celu1(a);
        }
        if constexpr (FHN > 0) {
            uint4* qo = (uint4*)(qnext + p * FHN);
#pragma unroll
            for (int s = 0; s < FHN / 8; ++s) {
                float qn[8];
#pragma unroll
                for (int k = 0; k < 8; ++k) {
                    int cn = s * 8 + k;
                    float a = ban[cn];
#pragma unroll
                    for (int c2 = 0; c2 < FOUT; ++c2)
                        a = fmaf(x[c2], wan[c2 * FHN + cn], a);
                    a = fmaf(p0, wan[(FOUT + 0) * FHN + cn], a);
                    a = fmaf(p1, wan[(FOUT + 1) * FHN + cn], a);
                    a = fmaf(p2, wan[(FOUT + 2) * FHN + cn], a);
                    qn[k] = a;
                }
                uint4 pk;
                pk.x = pack2(qn[0], qn[1]);
                pk.y = pack2(qn[2], qn[3]);
                pk.z = pack2(qn[4], qn[5]);
                pk.w = pack2(qn[6], qn[7]);
                qo[s] = pk;
            }
        }
    }
}

extern "C" void kernel_launch(void* const* d_in, const int* in_sizes, int n_in,
                              void* d_out, int out_size, void* d_ws, size_t ws_size,
                              hipStream_t stream) {
    const float* pos = (const float*)d_in[0];
    const int* idx = (const int*)d_in[4];
    const float* w1a = (const float*)d_in[5];
    const float* b1a = (const float*)d_in[6];
    const float* w1b = (const float*)d_in[7];
    const float* b1b = (const float*)d_in[8];
    const float* w2a = (const float*)d_in[9];
    const float* b2a = (const float*)d_in[10];
    const float* w2b = (const float*)d_in[11];
    const float* b2b = (const float*)d_in[12];
    const float* w3a = (const float*)d_in[13];
    const float* b3a = (const float*)d_in[14];
    const float* w3b = (const float*)d_in[15];
    const float* b3b = (const float*)d_in[16];
    float* out = (float*)d_out;

    // Compact 16MB workspace (fewer distinct lines touched => fewer forced
    // evictions of the harness's dirty poison fill).
    char* ws = (char*)d_ws;
    __half* A      = (__half*)ws;                         // 0..4MB: Q1 then Q3
    __half* B      = (__half*)(ws + (4u << 20));          // 4..6MB: Q2
    unsigned short* idxs = (unsigned short*)(ws + (6u << 20)); // 6..14MB
    int*    cid    = (int*)(ws + (14u << 20));            // 256KB
    int*    order  = (int*)(ws + (14u << 20) + (256u << 10)); // 256KB
    unsigned short* perm = (unsigned short*)(ws + (14u << 20) + (512u << 10)); // 128KB
    int*    hist   = (int*)(ws + (14u << 20) + (640u << 10));   // 16KB
    int*    cellptr= (int*)(ws + (14u << 20) + (656u << 10));   // 16KB
    float*  pos_s  = (float*)(ws + (15u << 20));          // 768KB

    hipMemsetAsync(hist, 0, NCELL * sizeof(int), stream);
    k_cell<<<NPTS / 256, 256, 0, stream>>>(pos, out, out_size, cid, hist);
    k_scan<<<1, 64, 0, stream>>>(hist, cellptr);
    k_scatter<<<NPTS / 256, 256, 0, stream>>>(pos, cid, cellptr, perm, order,
                                              pos_s, w1a, b1a, A);
    k_trans<<<NPTS * 8 / 256, 256, 0, stream>>>(idx, order, perm, idxs);

    k_layer<8, 8, 16, false><<<NPTS / TILE, 256, 0, stream>>>(
        A, idxs, pos_s, nullptr, w1a + 3 * 8, w1b, b1b, w2a, b2a, nullptr, B);
    k_layer<16, 16, 32, false><<<NPTS / TILE, 256, 0, stream>>>(
        B, idxs, pos_s, nullptr, w2a + 8 * 16, w2b, b2b, w3a, b3a, nullptr, A);
    k_layer<32, 32, 0, true><<<NPTS / TILE, 256, 0, stream>>>(
        A, idxs, pos_s, order, w3a + 16 * 32, w3b, b3b, nullptr, nullptr,
        out + 3 * NPTS, nullptr);
}